// Round 1
// baseline (120.118 us; speedup 1.0000x reference)
//
#include <hip/hip_runtime.h>
#include <cmath>

#define D_MODEL 1792
#define BB      256
#define II      2048          // inner dim
#define FOURI   8192

__device__ __forceinline__ float sigm(float v) { return 1.0f / (1.0f + expf(-v)); }

__device__ __forceinline__ float waveReduce(float s) {
    #pragma unroll
    for (int off = 32; off > 0; off >>= 1) s += __shfl_down(s, off, 64);
    return s;
}

// ---------------------------------------------------------------------------
// Kernel A: precompute gih[t][r] = Wih@inpt[t] + bih + bhh for t=0..4 (all 8192
// rows) and t=5 (only the 1024 rows feeding the last 256 h-outputs).
// One wave per row. Grid: 10240 + 256 = 10496 blocks of 256.
// ---------------------------------------------------------------------------
__global__ __launch_bounds__(256) void ih_kernel(
    const float* __restrict__ x,     // (6, 1792)
    const float* __restrict__ y,     // (5, 256)
    const float* __restrict__ Wih5,  // (5, 8192, 2048)
    const float* __restrict__ bih5,  // (5, 8192)
    const float* __restrict__ bhh5,  // (5, 8192)
    const float* __restrict__ WihF,  // (8192, 1792)
    const float* __restrict__ bihF,  // (8192)
    const float* __restrict__ bhhF,  // (8192)
    float* __restrict__ gih)         // (6, 8192)
{
    const int blk  = blockIdx.x;
    const int wave = threadIdx.x >> 6;
    const int lane = threadIdx.x & 63;

    if (blk < 10240) {
        const int t = blk >> 11;                    // 2048 blocks per step
        const int r = ((blk & 2047) << 2) + wave;   // [0, 8192)
        const float* wrow = Wih5 + ((size_t)t * FOURI + r) * (size_t)II;
        const float* xt = x + t * D_MODEL;
        const float* yt = y + t * BB;
        float sum = 0.f;
        #pragma unroll
        for (int p = 0; p < 8; ++p) {
            const int j = p * 256 + lane * 4;
            float4 w = *(const float4*)(wrow + j);
            float4 v = (p < 7) ? *(const float4*)(xt + j)
                               : *(const float4*)(yt + (j - D_MODEL));
            sum += w.x * v.x + w.y * v.y + w.z * v.z + w.w * v.w;
        }
        sum = waveReduce(sum);
        if (lane == 0)
            gih[t * FOURI + r] = sum + bih5[t * FOURI + r] + bhh5[t * FOURI + r];
    } else {
        // final-cell ih: rows q*2048 + 1792 + k, q in [0,4), k in [0,256)
        const int u = (blk - 10240) * 4 + wave;     // [0, 1024)
        const int q = u >> 8;
        const int k = u & 255;
        const int r = q * II + D_MODEL + k;
        const float* wrow = WihF + (size_t)r * (size_t)D_MODEL;
        const float* x5 = x + 5 * D_MODEL;
        float sum = 0.f;
        #pragma unroll
        for (int p = 0; p < 7; ++p) {
            const int j = p * 256 + lane * 4;
            float4 w = *(const float4*)(wrow + j);
            float4 v = *(const float4*)(x5 + j);
            sum += w.x * v.x + w.y * v.y + w.z * v.z + w.w * v.w;
        }
        sum = waveReduce(sum);
        if (lane == 0)
            gih[5 * FOURI + r] = sum + bihF[r] + bhhF[r];
    }
}

// ---------------------------------------------------------------------------
// Kernel B0: step 0 has h0=c0=0 -> no Whh matvec. Pure gate math.
// ---------------------------------------------------------------------------
__global__ __launch_bounds__(256) void step0_kernel(
    const float* __restrict__ gih,   // step-0 slice (8192)
    float* __restrict__ h_out,       // (2048)
    float* __restrict__ c_out)       // (2048)
{
    const int r = blockIdx.x * 256 + threadIdx.x;   // [0, 2048)
    const float gi = gih[r];
    const float gg = gih[2 * II + r];
    const float go = gih[3 * II + r];
    const float cc = sigm(gi) * tanhf(gg);          // f-gate * 0 drops out
    c_out[r] = cc;
    h_out[r] = sigm(go) * tanhf(cc);
}

// ---------------------------------------------------------------------------
// Kernel B: one recurrent step. Block = one h-row; wave q computes the q-th
// gate's dot(Whh_row, h_in). c updated in place (row owned by this block).
// ---------------------------------------------------------------------------
__global__ __launch_bounds__(256) void hh_step_kernel(
    const float* __restrict__ Whh,    // (8192, 2048) for this step
    const float* __restrict__ gih_t,  // (8192)
    const float* __restrict__ h_in,   // (2048)
    float* __restrict__ h_out,        // (2048)
    float* __restrict__ c)            // (2048), in place
{
    __shared__ float partial[4];
    const int r    = blockIdx.x;        // [0, 2048)
    const int wave = threadIdx.x >> 6;  // gate index
    const int lane = threadIdx.x & 63;

    const float* wrow = Whh + ((size_t)wave * II + r) * (size_t)II;
    float sum = 0.f;
    #pragma unroll
    for (int p = 0; p < 8; ++p) {
        const int j = p * 256 + lane * 4;
        float4 w = *(const float4*)(wrow + j);
        float4 v = *(const float4*)(h_in + j);
        sum += w.x * v.x + w.y * v.y + w.z * v.z + w.w * v.w;
    }
    sum = waveReduce(sum);
    if (lane == 0) partial[wave] = sum + gih_t[wave * II + r];
    __syncthreads();
    if (threadIdx.x == 0) {
        const float gi = partial[0], gf = partial[1], gg = partial[2], go = partial[3];
        const float cc = sigm(gf) * c[r] + sigm(gi) * tanhf(gg);
        c[r] = cc;
        h_out[r] = sigm(go) * tanhf(cc);
    }
}

// ---------------------------------------------------------------------------
// Kernel BF: final cell, only h-rows 1792..2047 are needed (output h[-256:]).
// Block = one output row; wave q computes gate q's dot over WhhF.
// ---------------------------------------------------------------------------
__global__ __launch_bounds__(256) void final_kernel(
    const float* __restrict__ WhhF,   // (8192, 2048)
    const float* __restrict__ gihF,   // (8192) precomputed ih part (+biases)
    const float* __restrict__ h_in,   // (2048)
    const float* __restrict__ c,      // (2048)
    float* __restrict__ out)          // (256)
{
    __shared__ float partial[4];
    const int k    = blockIdx.x;        // [0, 256)
    const int r    = D_MODEL + k;       // 1792 + k
    const int wave = threadIdx.x >> 6;
    const int lane = threadIdx.x & 63;

    const float* wrow = WhhF + ((size_t)wave * II + r) * (size_t)II;
    float sum = 0.f;
    #pragma unroll
    for (int p = 0; p < 8; ++p) {
        const int j = p * 256 + lane * 4;
        float4 w = *(const float4*)(wrow + j);
        float4 v = *(const float4*)(h_in + j);
        sum += w.x * v.x + w.y * v.y + w.z * v.z + w.w * v.w;
    }
    sum = waveReduce(sum);
    if (lane == 0) partial[wave] = sum + gihF[wave * II + r];
    __syncthreads();
    if (threadIdx.x == 0) {
        const float gi = partial[0], gf = partial[1], gg = partial[2], go = partial[3];
        const float cc = sigm(gf) * c[r] + sigm(gi) * tanhf(gg);
        out[k] = sigm(go) * tanhf(cc);
    }
}

extern "C" void kernel_launch(void* const* d_in, const int* in_sizes, int n_in,
                              void* d_out, int out_size, void* d_ws, size_t ws_size,
                              hipStream_t stream) {
    const float* x    = (const float*)d_in[0];
    const float* y    = (const float*)d_in[1];
    const float* Wih5 = (const float*)d_in[2];
    const float* Whh5 = (const float*)d_in[3];
    const float* bih5 = (const float*)d_in[4];
    const float* bhh5 = (const float*)d_in[5];
    const float* WihF = (const float*)d_in[6];
    const float* WhhF = (const float*)d_in[7];
    const float* bihF = (const float*)d_in[8];
    const float* bhhF = (const float*)d_in[9];
    float* out = (float*)d_out;

    float* ws   = (float*)d_ws;
    float* gih  = ws;                  // 6*8192 floats
    float* hA   = ws + 6 * FOURI;      // 2048
    float* hB   = hA + II;             // 2048
    float* cbuf = hB + II;             // 2048

    // A: all ih matvecs (independent of recurrence), biases folded in.
    ih_kernel<<<10496, 256, 0, stream>>>(x, y, Wih5, bih5, bhh5, WihF, bihF, bhhF, gih);

    // B0: step 0, h0=c0=0 so no Whh matvec needed.
    step0_kernel<<<II / 256, 256, 0, stream>>>(gih, hA, cbuf);

    // B1..B4: sequential recurrent steps, ping-pong h buffers.
    const float* hin = hA;
    float* hout = hB;
    for (int t = 1; t <= 4; ++t) {
        hh_step_kernel<<<II, 256, 0, stream>>>(
            Whh5 + (size_t)t * FOURI * II, gih + t * FOURI, hin, hout, cbuf);
        float* tmp = hout;
        hout = (float*)hin;
        hin = tmp;
    }

    // BF: final cell, only last 256 rows, writes output directly.
    final_kernel<<<BB, 256, 0, stream>>>(WhhF, gih + 5 * FOURI, hin, cbuf, out);
}